// Round 1
// baseline (11162.879 us; speedup 1.0000x reference)
//
#include <hip/hip_runtime.h>
#include <math.h>

#define WIDTH 256

__device__ __forceinline__ float gelu_exact(float v) {
    return 0.5f * v * (1.0f + erff(v * 0.70710678118654752f));
}

// ---------------- degree / norm precompute ----------------
__global__ void k_deg_init(float* __restrict__ dis, int n) {
    int i = blockIdx.x * blockDim.x + threadIdx.x;
    if (i < n) dis[i] = 1.0f;   // self-loop contributes 1 to every node's degree
}

__global__ void k_deg_count(const int* __restrict__ col, float* __restrict__ dis, int E) {
    int i = blockIdx.x * blockDim.x + threadIdx.x;
    if (i < E) atomicAdd(&dis[col[i]], 1.0f);
}

__global__ void k_deg_rsqrt(float* __restrict__ dis, int n) {
    int i = blockIdx.x * blockDim.x + threadIdx.x;
    if (i < n) dis[i] = rsqrtf(dis[i]);   // deg >= 1 always (self loop)
}

// ---------------- f32 GEMM: C[M,256] (64-col slice) = A[M,KDIM] x B ----------------
// BT=false: B is [KDIM][256] row-major (Wg layer weight, in->out)
// BT=true : B element (k,n) at B[n*KDIM+k]  (Wf is [256][KDIM=64])
// DO_GELU : C = gelu(acc + bias[col]) (foot); else raw store.
template <int KDIM, bool BT, bool DO_GELU>
__global__ __launch_bounds__(256) void k_gemm(const float* __restrict__ A,
                                              const float* __restrict__ B,
                                              const float* __restrict__ bias,
                                              float* __restrict__ C) {
    __shared__ float As[16][64];   // transposed: As[k][m]
    __shared__ float Bs[16][64];   // Bs[k][n]

    const int tid = threadIdx.x;
    const int tx = tid & 15;       // col group (4 cols each)
    const int ty = tid >> 4;       // row group (4 rows each)
    const int m0 = blockIdx.x * 64;
    const int n0 = blockIdx.y * 64;

    // A staging map: each thread loads float4 A[m0+am][k0+ak .. +3]
    const int am = tid >> 2;            // 0..63
    const int ak = (tid & 3) * 4;       // 0,4,8,12
    // B staging map: each thread loads Bs[bk][bn..bn+3]
    const int bk = tid >> 4;            // 0..15
    const int bn = (tid & 15) * 4;      // 0..60

    float acc[4][4] = {};

    for (int k0 = 0; k0 < KDIM; k0 += 16) {
        float4 av = *reinterpret_cast<const float4*>(&A[(size_t)(m0 + am) * KDIM + k0 + ak]);
        float4 bv;
        if (BT) {
            bv.x = B[(size_t)(n0 + bn + 0) * KDIM + k0 + bk];
            bv.y = B[(size_t)(n0 + bn + 1) * KDIM + k0 + bk];
            bv.z = B[(size_t)(n0 + bn + 2) * KDIM + k0 + bk];
            bv.w = B[(size_t)(n0 + bn + 3) * KDIM + k0 + bk];
        } else {
            bv = *reinterpret_cast<const float4*>(&B[(size_t)(k0 + bk) * WIDTH + n0 + bn]);
        }
        __syncthreads();   // previous iteration's reads done before overwrite
        As[ak + 0][am] = av.x;
        As[ak + 1][am] = av.y;
        As[ak + 2][am] = av.z;
        As[ak + 3][am] = av.w;
        *reinterpret_cast<float4*>(&Bs[bk][bn]) = bv;
        __syncthreads();

#pragma unroll
        for (int k = 0; k < 16; ++k) {
            const float4 a = *reinterpret_cast<const float4*>(&As[k][ty * 4]);
            const float4 b = *reinterpret_cast<const float4*>(&Bs[k][tx * 4]);
            const float ar[4] = {a.x, a.y, a.z, a.w};
            const float br[4] = {b.x, b.y, b.z, b.w};
#pragma unroll
            for (int i = 0; i < 4; ++i)
#pragma unroll
                for (int j = 0; j < 4; ++j)
                    acc[i][j] = fmaf(ar[i], br[j], acc[i][j]);
        }
    }

    const int colg = n0 + tx * 4;
#pragma unroll
    for (int i = 0; i < 4; ++i) {
        const int row = m0 + ty * 4 + i;
        float4 o;
        o.x = acc[i][0];
        o.y = acc[i][1];
        o.z = acc[i][2];
        o.w = acc[i][3];
        if (DO_GELU) {
            o.x = gelu_exact(o.x + bias[colg + 0]);
            o.y = gelu_exact(o.y + bias[colg + 1]);
            o.z = gelu_exact(o.z + bias[colg + 2]);
            o.w = gelu_exact(o.w + bias[colg + 3]);
        }
        *reinterpret_cast<float4*>(&C[(size_t)row * WIDTH + colg]) = o;
    }
}

// ---------------- self-loop + layer bias: h[i][c] += bg[c] + dis[i]^2 * xl[i][c] ----------------
__global__ __launch_bounds__(256) void k_selfloop(float* __restrict__ h,
                                                  const float* __restrict__ xl,
                                                  const float* __restrict__ dis,
                                                  const float* __restrict__ bg) {
    const int idx = blockIdx.x * 256 + threadIdx.x;   // float4 index, total N*64
    const int node = idx >> 6;
    const int c4 = (idx & 63) * 4;
    float w = dis[node];
    w = w * w;
    const float4 xv = *reinterpret_cast<const float4*>(&xl[(size_t)idx * 4]);
    float4 hv = *reinterpret_cast<const float4*>(&h[(size_t)idx * 4]);
    hv.x += bg[c4 + 0] + w * xv.x;
    hv.y += bg[c4 + 1] + w * xv.y;
    hv.z += bg[c4 + 2] + w * xv.z;
    hv.w += bg[c4 + 3] + w * xv.w;
    *reinterpret_cast<float4*>(&h[(size_t)idx * 4]) = hv;
}

// ---------------- edge scatter: h[col] += dis[row]*dis[col] * xl[row] ----------------
// one wave (64 lanes) per edge; lane handles 4 channels (float4)
__global__ __launch_bounds__(256) void k_scatter(const int* __restrict__ row,
                                                 const int* __restrict__ col,
                                                 const float* __restrict__ dis,
                                                 const float* __restrict__ xl,
                                                 float* __restrict__ h, int E) {
    const int e = blockIdx.x * 4 + (threadIdx.x >> 6);
    if (e >= E) return;
    const int lane = threadIdx.x & 63;
    const int r = row[e];
    const int c = col[e];
    const float w = dis[r] * dis[c];
    const float4 xv = *reinterpret_cast<const float4*>(&xl[(size_t)r * WIDTH + lane * 4]);
    float* hp = &h[(size_t)c * WIDTH + lane * 4];
    atomicAdd(hp + 0, w * xv.x);
    atomicAdd(hp + 1, w * xv.y);
    atomicAdd(hp + 2, w * xv.z);
    atomicAdd(hp + 3, w * xv.w);
}

// ---------------- head: out[g] = gelu(h[center[g]+ptr[g]]) @ Wh^T + bh ----------------
__global__ __launch_bounds__(256) void k_head(const float* __restrict__ h,
                                              const int* __restrict__ center,
                                              const int* __restrict__ ptr,
                                              const float* __restrict__ Wh,
                                              const float* __restrict__ bh,
                                              float* __restrict__ out) {
    __shared__ float gs[256];
    const int g = blockIdx.x;
    const int node = center[g] + ptr[g];
    gs[threadIdx.x] = gelu_exact(h[(size_t)node * WIDTH + threadIdx.x]);
    __syncthreads();
    if (threadIdx.x < 7) {
        float acc = bh[threadIdx.x];
        for (int k = 0; k < 256; ++k)
            acc = fmaf(gs[k], Wh[threadIdx.x * 256 + k], acc);
        out[g * 7 + threadIdx.x] = acc;
    }
}

extern "C" void kernel_launch(void* const* d_in, const int* in_sizes, int n_in,
                              void* d_out, int out_size, void* d_ws, size_t ws_size,
                              hipStream_t stream) {
    const float* x      = (const float*)d_in[0];
    const int*   ei     = (const int*)d_in[1];
    const int*   center = (const int*)d_in[2];
    const int*   ptr    = (const int*)d_in[3];
    const float* Wf     = (const float*)d_in[4];
    const float* bf     = (const float*)d_in[5];
    const float* Wg     = (const float*)d_in[6];
    const float* bg     = (const float*)d_in[7];
    const float* Wh     = (const float*)d_in[8];
    const float* bh     = (const float*)d_in[9];

    const int E = in_sizes[1] / 2;       // 799744
    const int N = in_sizes[0] / 64;      // 49984
    const int B = in_sizes[2];           // 32

    char* ws = (char*)d_ws;
    float* h   = (float*)ws;                                   // N*256 f32 = 51.2 MB
    float* xl  = (float*)(ws + (size_t)N * WIDTH * 4);         // N*256 f32 = 51.2 MB
    float* dis = (float*)(ws + (size_t)N * WIDTH * 4 * 2);     // N f32

    const int* rowv = ei;
    const int* colv = ei + E;

    k_deg_init<<<(N + 255) / 256, 256, 0, stream>>>(dis, N);
    k_deg_count<<<(E + 255) / 256, 256, 0, stream>>>(colv, dis, E);
    k_deg_rsqrt<<<(N + 255) / 256, 256, 0, stream>>>(dis, N);

    dim3 gg(N / 64, 4);
    // foot: h = gelu(x @ Wf^T + bf)
    k_gemm<64, true, true><<<gg, 256, 0, stream>>>(x, Wf, bf, h);

    for (int l = 0; l < 4; ++l) {
        // xl = h @ Wg[l]
        k_gemm<256, false, false><<<gg, 256, 0, stream>>>(h, Wg + (size_t)l * WIDTH * WIDTH, nullptr, xl);
        // h += bg[l] + dis^2 * xl   (self loop + bias)
        k_selfloop<<<(N * 64) / 256, 256, 0, stream>>>(h, xl, dis, bg + (size_t)l * WIDTH);
        // h[col] += dis[row]*dis[col] * xl[row]  over all edges
        k_scatter<<<(E + 3) / 4, 256, 0, stream>>>(rowv, colv, dis, xl, h, E);
    }

    k_head<<<B, 256, 0, stream>>>(h, center, ptr, Wh, bh, (float*)d_out);
}

// Round 2
// 1127.593 us; speedup vs baseline: 9.8997x; 9.8997x over previous
//
#include <hip/hip_runtime.h>
#include <math.h>

#define WIDTH 256

__device__ __forceinline__ float gelu_exact(float v) {
    return 0.5f * v * (1.0f + erff(v * 0.70710678118654752f));
}

// ---------------- CSR build ----------------
__global__ void k_zero_int(int* __restrict__ p, int n) {
    int i = blockIdx.x * blockDim.x + threadIdx.x;
    if (i < n) p[i] = 0;
}

__global__ void k_hist(const int* __restrict__ col, int* __restrict__ deg, int E) {
    int i = blockIdx.x * blockDim.x + threadIdx.x;
    if (i < E) atomicAdd(&deg[col[i]], 1);
}

__global__ void k_dis(const int* __restrict__ deg, float* __restrict__ dis, int n) {
    int i = blockIdx.x * blockDim.x + threadIdx.x;
    if (i < n) dis[i] = rsqrtf(1.0f + (float)deg[i]);   // +1 = self loop
}

// single-workgroup exclusive scan (N ~ 50K, trivial time)
__global__ __launch_bounds__(1024) void k_scan(const int* __restrict__ deg,
                                               int* __restrict__ off, int N) {
    __shared__ int buf[1024];
    __shared__ int base_s;
    const int t = threadIdx.x;
    if (t == 0) base_s = 0;
    __syncthreads();
    for (int c0 = 0; c0 < N; c0 += 1024) {
        const int idx = c0 + t;
        const int orig = (idx < N) ? deg[idx] : 0;
        buf[t] = orig;
        __syncthreads();
#pragma unroll
        for (int d = 1; d < 1024; d <<= 1) {
            int add = (t >= d) ? buf[t - d] : 0;
            __syncthreads();
            buf[t] += add;
            __syncthreads();
        }
        const int incl = buf[t];
        if (idx < N) off[idx] = base_s + incl - orig;
        __syncthreads();
        if (t == 1023) base_s += incl;   // chunk total
        __syncthreads();
    }
    if (t == 0) off[N] = base_s;
}

__global__ void k_copy_int(const int* __restrict__ src, int* __restrict__ dst, int n) {
    int i = blockIdx.x * blockDim.x + threadIdx.x;
    if (i < n) dst[i] = src[i];
}

__global__ void k_fill(const int* __restrict__ row, const int* __restrict__ col,
                       int* __restrict__ cursor, int* __restrict__ csr_src, int E) {
    int i = blockIdx.x * blockDim.x + threadIdx.x;
    if (i < E) {
        int pos = atomicAdd(&cursor[col[i]], 1);
        csr_src[pos] = row[i];
    }
}

// ---------------- f32 GEMM: C[M,256] (64-col slice) = A[M,KDIM] x B ----------------
template <int KDIM, bool BT, bool DO_GELU>
__global__ __launch_bounds__(256) void k_gemm(const float* __restrict__ A,
                                              const float* __restrict__ B,
                                              const float* __restrict__ bias,
                                              float* __restrict__ C) {
    __shared__ float As[16][64];   // transposed: As[k][m]
    __shared__ float Bs[16][64];   // Bs[k][n]

    const int tid = threadIdx.x;
    const int tx = tid & 15;
    const int ty = tid >> 4;
    const int m0 = blockIdx.x * 64;
    const int n0 = blockIdx.y * 64;

    const int am = tid >> 2;
    const int ak = (tid & 3) * 4;
    const int bk = tid >> 4;
    const int bn = (tid & 15) * 4;

    float acc[4][4] = {};

    for (int k0 = 0; k0 < KDIM; k0 += 16) {
        float4 av = *reinterpret_cast<const float4*>(&A[(size_t)(m0 + am) * KDIM + k0 + ak]);
        float4 bv;
        if (BT) {
            bv.x = B[(size_t)(n0 + bn + 0) * KDIM + k0 + bk];
            bv.y = B[(size_t)(n0 + bn + 1) * KDIM + k0 + bk];
            bv.z = B[(size_t)(n0 + bn + 2) * KDIM + k0 + bk];
            bv.w = B[(size_t)(n0 + bn + 3) * KDIM + k0 + bk];
        } else {
            bv = *reinterpret_cast<const float4*>(&B[(size_t)(k0 + bk) * WIDTH + n0 + bn]);
        }
        __syncthreads();
        As[ak + 0][am] = av.x;
        As[ak + 1][am] = av.y;
        As[ak + 2][am] = av.z;
        As[ak + 3][am] = av.w;
        *reinterpret_cast<float4*>(&Bs[bk][bn]) = bv;
        __syncthreads();

#pragma unroll
        for (int k = 0; k < 16; ++k) {
            const float4 a = *reinterpret_cast<const float4*>(&As[k][ty * 4]);
            const float4 b = *reinterpret_cast<const float4*>(&Bs[k][tx * 4]);
            const float ar[4] = {a.x, a.y, a.z, a.w};
            const float br[4] = {b.x, b.y, b.z, b.w};
#pragma unroll
            for (int i = 0; i < 4; ++i)
#pragma unroll
                for (int j = 0; j < 4; ++j)
                    acc[i][j] = fmaf(ar[i], br[j], acc[i][j]);
        }
    }

    const int colg = n0 + tx * 4;
#pragma unroll
    for (int i = 0; i < 4; ++i) {
        const int row = m0 + ty * 4 + i;
        float4 o;
        o.x = acc[i][0];
        o.y = acc[i][1];
        o.z = acc[i][2];
        o.w = acc[i][3];
        if (DO_GELU) {
            o.x = gelu_exact(o.x + bias[colg + 0]);
            o.y = gelu_exact(o.y + bias[colg + 1]);
            o.z = gelu_exact(o.z + bias[colg + 2]);
            o.w = gelu_exact(o.w + bias[colg + 3]);
        }
        *reinterpret_cast<float4*>(&C[(size_t)row * WIDTH + colg]) = o;
    }
}

// ---------------- fused aggregate: h[i] += bg + dis[i]^2*xl[i] + dis[i]*sum_e dis[s]*xl[s] ----------------
// one block (256 threads) per node; thread = channel
__global__ __launch_bounds__(256) void k_aggregate(const int* __restrict__ off,
                                                   const int* __restrict__ csr_src,
                                                   const float* __restrict__ dis,
                                                   const float* __restrict__ xl,
                                                   const float* __restrict__ bg,
                                                   float* __restrict__ h) {
    __shared__ int   s_src[256];
    __shared__ float s_dis[256];

    const int i = blockIdx.x;
    const int t = threadIdx.x;
    const int e0 = off[i];
    const int e1 = off[i + 1];
    const float di = dis[i];

    float acc = 0.0f;   // sum over in-edges of dis[s]*xl[s][t]
    for (int base = e0; base < e1; base += 256) {
        const int m = min(256, e1 - base);
        if (t < m) {
            const int s = csr_src[base + t];
            s_src[t] = s;
            s_dis[t] = dis[s];
        }
        __syncthreads();
        for (int j = 0; j < m; ++j)
            acc = fmaf(s_dis[j], xl[(size_t)s_src[j] * WIDTH + t], acc);
        __syncthreads();
    }

    const size_t p = (size_t)i * WIDTH + t;
    h[p] += bg[t] + di * di * xl[p] + di * acc;
}

// ---------------- head ----------------
__global__ __launch_bounds__(256) void k_head(const float* __restrict__ h,
                                              const int* __restrict__ center,
                                              const int* __restrict__ ptr,
                                              const float* __restrict__ Wh,
                                              const float* __restrict__ bh,
                                              float* __restrict__ out) {
    __shared__ float gs[256];
    const int g = blockIdx.x;
    const int node = center[g] + ptr[g];
    gs[threadIdx.x] = gelu_exact(h[(size_t)node * WIDTH + threadIdx.x]);
    __syncthreads();
    if (threadIdx.x < 7) {
        float acc = bh[threadIdx.x];
        for (int k = 0; k < 256; ++k)
            acc = fmaf(gs[k], Wh[threadIdx.x * 256 + k], acc);
        out[g * 7 + threadIdx.x] = acc;
    }
}

extern "C" void kernel_launch(void* const* d_in, const int* in_sizes, int n_in,
                              void* d_out, int out_size, void* d_ws, size_t ws_size,
                              hipStream_t stream) {
    const float* x      = (const float*)d_in[0];
    const int*   ei     = (const int*)d_in[1];
    const int*   center = (const int*)d_in[2];
    const int*   ptr    = (const int*)d_in[3];
    const float* Wf     = (const float*)d_in[4];
    const float* bf     = (const float*)d_in[5];
    const float* Wg     = (const float*)d_in[6];
    const float* bg     = (const float*)d_in[7];
    const float* Wh     = (const float*)d_in[8];
    const float* bh     = (const float*)d_in[9];

    const int E = in_sizes[1] / 2;       // 799744
    const int N = in_sizes[0] / 64;      // 49984
    const int B = in_sizes[2];           // 32

    char* ws = (char*)d_ws;
    size_t o = 0;
    float* h       = (float*)(ws + o); o += (size_t)N * WIDTH * 4;   // 51.2 MB
    float* xl      = (float*)(ws + o); o += (size_t)N * WIDTH * 4;   // 51.2 MB
    float* dis     = (float*)(ws + o); o += (size_t)N * 4;
    int*   deg     = (int*)  (ws + o); o += (size_t)N * 4;
    int*   off     = (int*)  (ws + o); o += (size_t)(N + 1) * 4;
    int*   cursor  = (int*)  (ws + o); o += (size_t)N * 4;
    int*   csr_src = (int*)  (ws + o); o += (size_t)E * 4;           // 3.2 MB

    const int* rowv = ei;
    const int* colv = ei + E;

    const int nb = (N + 255) / 256;
    const int eb = (E + 255) / 256;

    // CSR by destination + norm
    k_zero_int<<<nb, 256, 0, stream>>>(deg, N);
    k_hist<<<eb, 256, 0, stream>>>(colv, deg, E);
    k_dis<<<nb, 256, 0, stream>>>(deg, dis, N);
    k_scan<<<1, 1024, 0, stream>>>(deg, off, N);
    k_copy_int<<<nb, 256, 0, stream>>>(off, cursor, N);
    k_fill<<<eb, 256, 0, stream>>>(rowv, colv, cursor, csr_src, E);

    dim3 gg(N / 64, 4);
    // foot: h = gelu(x @ Wf^T + bf)
    k_gemm<64, true, true><<<gg, 256, 0, stream>>>(x, Wf, bf, h);

    for (int l = 0; l < 4; ++l) {
        // xl = h @ Wg[l]
        k_gemm<256, false, false><<<gg, 256, 0, stream>>>(h, Wg + (size_t)l * WIDTH * WIDTH, nullptr, xl);
        // h += bg + dis^2*xl + dis * sum_edges dis[s]*xl[s]
        k_aggregate<<<N, 256, 0, stream>>>(off, csr_src, dis, xl, bg + (size_t)l * WIDTH, h);
    }

    k_head<<<B, 256, 0, stream>>>(h, center, ptr, Wh, bh, (float*)d_out);
}

// Round 3
// 635.234 us; speedup vs baseline: 17.5729x; 1.7751x over previous
//
#include <hip/hip_runtime.h>
#include <math.h>

#define WIDTH 256
typedef unsigned short u16;
typedef unsigned int u32;
typedef __attribute__((ext_vector_type(4))) float f32x4;
typedef __attribute__((ext_vector_type(8))) short bf16x8;

__device__ __forceinline__ float gelu_exact(float v) {
    return 0.5f * v * (1.0f + erff(v * 0.70710678118654752f));
}
__device__ __forceinline__ u16 f2b(float x) {   // f32 -> bf16 RTNE
    u32 u = __builtin_bit_cast(u32, x);
    return (u16)((u + 0x7fffu + ((u >> 16) & 1u)) >> 16);
}
__device__ __forceinline__ float b2f(u16 b) {
    u32 u = ((u32)b) << 16;
    return __builtin_bit_cast(float, u);
}

// ---------------- CSR build ----------------
__global__ void k_zero_int(int* __restrict__ p, int n) {
    int i = blockIdx.x * blockDim.x + threadIdx.x;
    if (i < n) p[i] = 0;
}

__global__ void k_hist(const int* __restrict__ col, int* __restrict__ deg, int E) {
    int i = blockIdx.x * blockDim.x + threadIdx.x;
    if (i < E) atomicAdd(&deg[col[i]], 1);
}

__global__ void k_dis(const int* __restrict__ deg, float* __restrict__ dis, int n) {
    int i = blockIdx.x * blockDim.x + threadIdx.x;
    if (i < n) dis[i] = rsqrtf(1.0f + (float)deg[i]);   // +1 = self loop
}

// hierarchical exclusive scan: per-block scan -> scan of block totals -> add base
__global__ __launch_bounds__(256) void k_scan1(const int* __restrict__ deg, int* __restrict__ off,
                                               int* __restrict__ part, int N) {
    __shared__ int buf[256];
    const int t = threadIdx.x;
    const int gid = blockIdx.x * 256 + t;
    const int v = (gid < N) ? deg[gid] : 0;
    buf[t] = v;
    __syncthreads();
#pragma unroll
    for (int d = 1; d < 256; d <<= 1) {
        int add = (t >= d) ? buf[t - d] : 0;
        __syncthreads();
        buf[t] += add;
        __syncthreads();
    }
    if (gid < N) off[gid] = buf[t] - v;            // block-local exclusive
    if (t == 255) part[blockIdx.x] = buf[255];     // block total
}

__global__ __launch_bounds__(256) void k_scan2(int* __restrict__ part, int NB) {
    __shared__ int buf[256];
    const int t = threadIdx.x;
    int v = (t < NB) ? part[t] : 0;
    buf[t] = v;
    __syncthreads();
#pragma unroll
    for (int d = 1; d < 256; d <<= 1) {
        int add = (t >= d) ? buf[t - d] : 0;
        __syncthreads();
        buf[t] += add;
        __syncthreads();
    }
    if (t < NB) part[t] = buf[t] - v;              // exclusive block base
}

__global__ __launch_bounds__(256) void k_scan3(int* __restrict__ off, const int* __restrict__ part,
                                               int* __restrict__ cursor, int N, int E) {
    const int gid = blockIdx.x * 256 + threadIdx.x;
    if (gid < N) {
        int o = off[gid] + part[blockIdx.x];
        off[gid] = o;
        cursor[gid] = o;
    }
    if (gid == 0) off[N] = E;
}

__global__ void k_fill(const int* __restrict__ row, const int* __restrict__ col,
                       int* __restrict__ cursor, int* __restrict__ csr_src, int E) {
    int i = blockIdx.x * blockDim.x + threadIdx.x;
    if (i < E) {
        int pos = atomicAdd(&cursor[col[i]], 1);
        csr_src[pos] = row[i];
    }
}

// ---------------- Wg -> WgT bf16 (per layer transposed weight) ----------------
__global__ void k_prep_wgt(const float* __restrict__ Wg, u16* __restrict__ WgT, int total) {
    int idx = blockIdx.x * blockDim.x + threadIdx.x;
    if (idx >= total) return;
    int l = idx >> 16;
    int k = (idx >> 8) & 255;
    int n = idx & 255;
    WgT[(size_t)l * 65536 + (size_t)n * 256 + k] = f2b(Wg[idx]);
}

// ---------------- foot f32 GEMM (K=64, B^T), gelu epilogue, writes h f32 + hb bf16 ----------------
template <int KDIM>
__global__ __launch_bounds__(256) void k_gemm_foot(const float* __restrict__ A,
                                                   const float* __restrict__ B,
                                                   const float* __restrict__ bias,
                                                   float* __restrict__ C,
                                                   u16* __restrict__ Cb) {
    __shared__ float As[16][64];
    __shared__ float Bs[16][64];

    const int tid = threadIdx.x;
    const int tx = tid & 15;
    const int ty = tid >> 4;
    const int m0 = blockIdx.x * 64;
    const int n0 = blockIdx.y * 64;

    const int am = tid >> 2;
    const int ak = (tid & 3) * 4;
    const int bk = tid >> 4;
    const int bn = (tid & 15) * 4;

    float acc[4][4] = {};

    for (int k0 = 0; k0 < KDIM; k0 += 16) {
        float4 av = *reinterpret_cast<const float4*>(&A[(size_t)(m0 + am) * KDIM + k0 + ak]);
        float4 bv;
        bv.x = B[(size_t)(n0 + bn + 0) * KDIM + k0 + bk];
        bv.y = B[(size_t)(n0 + bn + 1) * KDIM + k0 + bk];
        bv.z = B[(size_t)(n0 + bn + 2) * KDIM + k0 + bk];
        bv.w = B[(size_t)(n0 + bn + 3) * KDIM + k0 + bk];
        __syncthreads();
        As[ak + 0][am] = av.x;
        As[ak + 1][am] = av.y;
        As[ak + 2][am] = av.z;
        As[ak + 3][am] = av.w;
        *reinterpret_cast<float4*>(&Bs[bk][bn]) = bv;
        __syncthreads();

#pragma unroll
        for (int k = 0; k < 16; ++k) {
            const float4 a = *reinterpret_cast<const float4*>(&As[k][ty * 4]);
            const float4 b = *reinterpret_cast<const float4*>(&Bs[k][tx * 4]);
            const float ar[4] = {a.x, a.y, a.z, a.w};
            const float br[4] = {b.x, b.y, b.z, b.w};
#pragma unroll
            for (int i = 0; i < 4; ++i)
#pragma unroll
                for (int j = 0; j < 4; ++j)
                    acc[i][j] = fmaf(ar[i], br[j], acc[i][j]);
        }
    }

    const int colg = n0 + tx * 4;
#pragma unroll
    for (int i = 0; i < 4; ++i) {
        const int row = m0 + ty * 4 + i;
        float4 o;
        o.x = gelu_exact(acc[i][0] + bias[colg + 0]);
        o.y = gelu_exact(acc[i][1] + bias[colg + 1]);
        o.z = gelu_exact(acc[i][2] + bias[colg + 2]);
        o.w = gelu_exact(acc[i][3] + bias[colg + 3]);
        *reinterpret_cast<float4*>(&C[(size_t)row * WIDTH + colg]) = o;
        ushort4 ob;
        ob.x = f2b(o.x); ob.y = f2b(o.y); ob.z = f2b(o.z); ob.w = f2b(o.w);
        *reinterpret_cast<ushort4*>(&Cb[(size_t)row * WIDTH + colg]) = ob;
    }
}

// ---------------- layer GEMM: xlb[M,256] = hb[M,256] @ Wg (bf16 MFMA, f32 accum) ----------------
// block = 64 rows x 256 cols, 4 waves; wave w owns cols [64w,64w+64); BK=32, 8 k-steps.
__global__ __launch_bounds__(256) void k_gemm_bf16(const u16* __restrict__ hb,
                                                   const u16* __restrict__ WgT,
                                                   u16* __restrict__ xlb) {
    __shared__ u16 As[64 * 32];    // A[row][k] row-major, row stride 32 elems
    __shared__ u16 Bs[256 * 32];   // B^T[n][k] row-major

    const int tid = threadIdx.x;
    const int w = tid >> 6;
    const int l = tid & 63;
    const int m0 = blockIdx.x * 64;

    f32x4 acc[4][4] = {};

    // A staging: lane l of wave w -> row m0 + w*16 + (l>>2), elem k0 + (l&3)*8 (16B)
    const size_t a_src = (size_t)(m0 + w * 16 + (l >> 2)) * WIDTH + (size_t)((l & 3) * 8);
    u16* const as_dst = As + w * 16 * 32;   // HW adds lane*16B

    for (int ks = 0; ks < 8; ++ks) {
        const int k0 = ks * 32;
        __builtin_amdgcn_global_load_lds(
            (const __attribute__((address_space(1))) u32*)(hb + a_src + k0),
            (__attribute__((address_space(3))) u32*)as_dst, 16, 0, 0);
#pragma unroll
        for (int j = 0; j < 4; ++j) {
            const u16* bsrc = WgT + (size_t)(w * 64 + j * 16 + (l >> 2)) * WIDTH + k0 + (l & 3) * 8;
            __builtin_amdgcn_global_load_lds(
                (const __attribute__((address_space(1))) u32*)bsrc,
                (__attribute__((address_space(3))) u32*)(Bs + (w * 64 + j * 16) * 32), 16, 0, 0);
        }
        asm volatile("s_waitcnt vmcnt(0)" ::: "memory");
        __syncthreads();

        bf16x8 a[4], b[4];
#pragma unroll
        for (int fr = 0; fr < 4; ++fr)
            a[fr] = *reinterpret_cast<const bf16x8*>(&As[(fr * 16 + (l & 15)) * 32 + (l >> 4) * 8]);
#pragma unroll
        for (int fc = 0; fc < 4; ++fc)
            b[fc] = *reinterpret_cast<const bf16x8*>(&Bs[(w * 64 + fc * 16 + (l & 15)) * 32 + (l >> 4) * 8]);
#pragma unroll
        for (int fr = 0; fr < 4; ++fr)
#pragma unroll
            for (int fc = 0; fc < 4; ++fc)
                acc[fr][fc] = __builtin_amdgcn_mfma_f32_16x16x32_bf16(a[fr], b[fc], acc[fr][fc], 0, 0, 0);
        __syncthreads();
    }

    const int r0 = (l >> 4) * 4;
    const int ci = l & 15;
#pragma unroll
    for (int fr = 0; fr < 4; ++fr)
#pragma unroll
        for (int fc = 0; fc < 4; ++fc) {
            const int col = w * 64 + fc * 16 + ci;
#pragma unroll
            for (int r = 0; r < 4; ++r) {
                const int row = m0 + fr * 16 + r0 + r;
                xlb[(size_t)row * WIDTH + col] = f2b(acc[fr][fc][r]);
            }
        }
}

// ---------------- fused aggregate (bf16 gather, f32 accum/residual) ----------------
// h[i] += bg + dis[i]^2*xl[i] + dis[i]*sum_e dis[s]*xl[s];  hb = bf16(h)
__global__ __launch_bounds__(256) void k_aggregate(const int* __restrict__ off,
                                                   const int* __restrict__ csr_src,
                                                   const float* __restrict__ dis,
                                                   const u16* __restrict__ xlb,
                                                   const float* __restrict__ bg,
                                                   float* __restrict__ h,
                                                   u16* __restrict__ hb) {
    __shared__ int   s_src[256];
    __shared__ float s_dis[256];

    const int i = blockIdx.x;
    const int t = threadIdx.x;
    const int e0 = off[i];
    const int e1 = off[i + 1];
    const float di = dis[i];

    float acc = 0.0f;
    for (int base = e0; base < e1; base += 256) {
        const int m = min(256, e1 - base);
        if (t < m) {
            const int s = csr_src[base + t];
            s_src[t] = s;
            s_dis[t] = dis[s];
        }
        __syncthreads();
        for (int j = 0; j < m; ++j)
            acc = fmaf(s_dis[j], b2f(xlb[(size_t)s_src[j] * WIDTH + t]), acc);
        __syncthreads();
    }

    const size_t p = (size_t)i * WIDTH + t;
    const float hv = h[p] + bg[t] + di * di * b2f(xlb[p]) + di * acc;
    h[p] = hv;
    hb[p] = f2b(hv);
}

// ---------------- head ----------------
__global__ __launch_bounds__(256) void k_head(const float* __restrict__ h,
                                              const int* __restrict__ center,
                                              const int* __restrict__ ptr,
                                              const float* __restrict__ Wh,
                                              const float* __restrict__ bh,
                                              float* __restrict__ out) {
    __shared__ float gs[256];
    const int g = blockIdx.x;
    const int node = center[g] + ptr[g];
    gs[threadIdx.x] = gelu_exact(h[(size_t)node * WIDTH + threadIdx.x]);
    __syncthreads();
    if (threadIdx.x < 7) {
        float acc = bh[threadIdx.x];
        for (int k = 0; k < 256; ++k)
            acc = fmaf(gs[k], Wh[threadIdx.x * 256 + k], acc);
        out[g * 7 + threadIdx.x] = acc;
    }
}

extern "C" void kernel_launch(void* const* d_in, const int* in_sizes, int n_in,
                              void* d_out, int out_size, void* d_ws, size_t ws_size,
                              hipStream_t stream) {
    const float* x      = (const float*)d_in[0];
    const int*   ei     = (const int*)d_in[1];
    const int*   center = (const int*)d_in[2];
    const int*   ptr    = (const int*)d_in[3];
    const float* Wf     = (const float*)d_in[4];
    const float* bf     = (const float*)d_in[5];
    const float* Wg     = (const float*)d_in[6];
    const float* bg     = (const float*)d_in[7];
    const float* Wh     = (const float*)d_in[8];
    const float* bh     = (const float*)d_in[9];

    const int E = in_sizes[1] / 2;       // 799744
    const int N = in_sizes[0] / 64;      // 49984
    const int B = in_sizes[2];           // 32

    char* ws = (char*)d_ws;
    size_t o = 0;
    float* h       = (float*)(ws + o); o += (size_t)N * WIDTH * 4;   // 51.2 MB
    u16*   hb      = (u16*)  (ws + o); o += (size_t)N * WIDTH * 2;   // 25.6 MB
    u16*   xlb     = (u16*)  (ws + o); o += (size_t)N * WIDTH * 2;   // 25.6 MB
    float* dis     = (float*)(ws + o); o += (size_t)N * 4;
    int*   deg     = (int*)  (ws + o); o += (size_t)N * 4;
    int*   off     = (int*)  (ws + o); o += (size_t)(N + 1) * 4;
    int*   cursor  = (int*)  (ws + o); o += (size_t)N * 4;
    int*   part    = (int*)  (ws + o); o += 1024;
    int*   csr_src = (int*)  (ws + o); o += (size_t)E * 4;           // 3.2 MB
    u16*   WgT     = (u16*)  (ws + o); o += (size_t)4 * 65536 * 2;   // 0.5 MB

    const int* rowv = ei;
    const int* colv = ei + E;

    const int nb = (N + 255) / 256;   // 196
    const int eb = (E + 255) / 256;

    // CSR by destination + norm
    k_zero_int<<<nb, 256, 0, stream>>>(deg, N);
    k_hist<<<eb, 256, 0, stream>>>(colv, deg, E);
    k_dis<<<nb, 256, 0, stream>>>(deg, dis, N);
    k_scan1<<<nb, 256, 0, stream>>>(deg, off, part, N);
    k_scan2<<<1, 256, 0, stream>>>(part, nb);
    k_scan3<<<nb, 256, 0, stream>>>(off, part, cursor, N, E);
    k_fill<<<eb, 256, 0, stream>>>(rowv, colv, cursor, csr_src, E);

    // bf16 transposed layer weights
    k_prep_wgt<<<(4 * 65536 + 255) / 256, 256, 0, stream>>>(Wg, WgT, 4 * 65536);

    // foot: h = gelu(x @ Wf^T + bf), also hb = bf16(h)
    dim3 gg(N / 64, 4);
    k_gemm_foot<64><<<gg, 256, 0, stream>>>(x, Wf, bf, h, hb);

    for (int l = 0; l < 4; ++l) {
        k_gemm_bf16<<<N / 64, 256, 0, stream>>>(hb, WgT + (size_t)l * 65536, xlb);
        k_aggregate<<<N, 256, 0, stream>>>(off, csr_src, dis, xlb, bg + (size_t)l * WIDTH, h, hb);
    }

    k_head<<<B, 256, 0, stream>>>(h, center, ptr, Wh, bh, (float*)d_out);
}

// Round 4
// 516.794 us; speedup vs baseline: 21.6003x; 1.2292x over previous
//
#include <hip/hip_runtime.h>
#include <math.h>

#define WIDTH 256
typedef unsigned short u16;
typedef unsigned int u32;
typedef __attribute__((ext_vector_type(4))) float f32x4;
typedef __attribute__((ext_vector_type(8))) short bf16x8;

__device__ __forceinline__ float gelu_exact(float v) {
    return 0.5f * v * (1.0f + erff(v * 0.70710678118654752f));
}
__device__ __forceinline__ u16 f2b(float x) {   // f32 -> bf16 RTNE
    u32 u = __builtin_bit_cast(u32, x);
    return (u16)((u + 0x7fffu + ((u >> 16) & 1u)) >> 16);
}
__device__ __forceinline__ float b2f(u16 b) {
    u32 u = ((u32)b) << 16;
    return __builtin_bit_cast(float, u);
}
__device__ __forceinline__ float b2f_lo(u32 v) {   // low u16 -> f32
    return __builtin_bit_cast(float, v << 16);
}
__device__ __forceinline__ float b2f_hi(u32 v) {   // high u16 -> f32
    return __builtin_bit_cast(float, v & 0xffff0000u);
}

// ---------------- CSR build ----------------
__global__ void k_zero_int(int* __restrict__ p, int n) {
    int i = blockIdx.x * blockDim.x + threadIdx.x;
    if (i < n) p[i] = 0;
}

__global__ void k_hist(const int* __restrict__ col, int* __restrict__ deg, int E) {
    int i = blockIdx.x * blockDim.x + threadIdx.x;
    if (i < E) atomicAdd(&deg[col[i]], 1);
}

__global__ void k_dis(const int* __restrict__ deg, float* __restrict__ dis, int n) {
    int i = blockIdx.x * blockDim.x + threadIdx.x;
    if (i < n) dis[i] = rsqrtf(1.0f + (float)deg[i]);   // +1 = self loop
}

// hierarchical exclusive scan
__global__ __launch_bounds__(256) void k_scan1(const int* __restrict__ deg, int* __restrict__ off,
                                               int* __restrict__ part, int N) {
    __shared__ int buf[256];
    const int t = threadIdx.x;
    const int gid = blockIdx.x * 256 + t;
    const int v = (gid < N) ? deg[gid] : 0;
    buf[t] = v;
    __syncthreads();
#pragma unroll
    for (int d = 1; d < 256; d <<= 1) {
        int add = (t >= d) ? buf[t - d] : 0;
        __syncthreads();
        buf[t] += add;
        __syncthreads();
    }
    if (gid < N) off[gid] = buf[t] - v;
    if (t == 255) part[blockIdx.x] = buf[255];
}

__global__ __launch_bounds__(256) void k_scan2(int* __restrict__ part, int NB) {
    __shared__ int buf[256];
    const int t = threadIdx.x;
    int v = (t < NB) ? part[t] : 0;
    buf[t] = v;
    __syncthreads();
#pragma unroll
    for (int d = 1; d < 256; d <<= 1) {
        int add = (t >= d) ? buf[t - d] : 0;
        __syncthreads();
        buf[t] += add;
        __syncthreads();
    }
    if (t < NB) part[t] = buf[t] - v;
}

__global__ __launch_bounds__(256) void k_scan3(int* __restrict__ off, const int* __restrict__ part,
                                               int* __restrict__ cursor, int N, int E) {
    const int gid = blockIdx.x * 256 + threadIdx.x;
    if (gid < N) {
        int o = off[gid] + part[blockIdx.x];
        off[gid] = o;
        cursor[gid] = o;
    }
    if (gid == 0) off[N] = E;
}

__global__ void k_fill(const int* __restrict__ row, const int* __restrict__ col,
                       int* __restrict__ cursor, int* __restrict__ csr_src, int E) {
    int i = blockIdx.x * blockDim.x + threadIdx.x;
    if (i < E) {
        int pos = atomicAdd(&cursor[col[i]], 1);
        csr_src[pos] = row[i];
    }
}

// ---------------- Wg -> WgT bf16 ----------------
__global__ void k_prep_wgt(const float* __restrict__ Wg, u16* __restrict__ WgT, int total) {
    int idx = blockIdx.x * blockDim.x + threadIdx.x;
    if (idx >= total) return;
    int l = idx >> 16;
    int k = (idx >> 8) & 255;
    int n = idx & 255;
    WgT[(size_t)l * 65536 + (size_t)n * 256 + k] = f2b(Wg[idx]);
}

// ---------------- foot f32 GEMM (K=64, B^T), gelu epilogue, writes h f32 + hb bf16 ----------------
template <int KDIM>
__global__ __launch_bounds__(256) void k_gemm_foot(const float* __restrict__ A,
                                                   const float* __restrict__ B,
                                                   const float* __restrict__ bias,
                                                   float* __restrict__ C,
                                                   u16* __restrict__ Cb) {
    __shared__ float As[16][64];
    __shared__ float Bs[16][64];

    const int tid = threadIdx.x;
    const int tx = tid & 15;
    const int ty = tid >> 4;
    const int m0 = blockIdx.x * 64;
    const int n0 = blockIdx.y * 64;

    const int am = tid >> 2;
    const int ak = (tid & 3) * 4;
    const int bk = tid >> 4;
    const int bn = (tid & 15) * 4;

    float acc[4][4] = {};

    for (int k0 = 0; k0 < KDIM; k0 += 16) {
        float4 av = *reinterpret_cast<const float4*>(&A[(size_t)(m0 + am) * KDIM + k0 + ak]);
        float4 bv;
        bv.x = B[(size_t)(n0 + bn + 0) * KDIM + k0 + bk];
        bv.y = B[(size_t)(n0 + bn + 1) * KDIM + k0 + bk];
        bv.z = B[(size_t)(n0 + bn + 2) * KDIM + k0 + bk];
        bv.w = B[(size_t)(n0 + bn + 3) * KDIM + k0 + bk];
        __syncthreads();
        As[ak + 0][am] = av.x;
        As[ak + 1][am] = av.y;
        As[ak + 2][am] = av.z;
        As[ak + 3][am] = av.w;
        *reinterpret_cast<float4*>(&Bs[bk][bn]) = bv;
        __syncthreads();

#pragma unroll
        for (int k = 0; k < 16; ++k) {
            const float4 a = *reinterpret_cast<const float4*>(&As[k][ty * 4]);
            const float4 b = *reinterpret_cast<const float4*>(&Bs[k][tx * 4]);
            const float ar[4] = {a.x, a.y, a.z, a.w};
            const float br[4] = {b.x, b.y, b.z, b.w};
#pragma unroll
            for (int i = 0; i < 4; ++i)
#pragma unroll
                for (int j = 0; j < 4; ++j)
                    acc[i][j] = fmaf(ar[i], br[j], acc[i][j]);
        }
    }

    const int colg = n0 + tx * 4;
#pragma unroll
    for (int i = 0; i < 4; ++i) {
        const int row = m0 + ty * 4 + i;
        float4 o;
        o.x = gelu_exact(acc[i][0] + bias[colg + 0]);
        o.y = gelu_exact(acc[i][1] + bias[colg + 1]);
        o.z = gelu_exact(acc[i][2] + bias[colg + 2]);
        o.w = gelu_exact(acc[i][3] + bias[colg + 3]);
        *reinterpret_cast<float4*>(&C[(size_t)row * WIDTH + colg]) = o;
        ushort4 ob;
        ob.x = f2b(o.x); ob.y = f2b(o.y); ob.z = f2b(o.z); ob.w = f2b(o.w);
        *reinterpret_cast<ushort4*>(&Cb[(size_t)row * WIDTH + colg]) = ob;
    }
}

// ---------------- layer GEMM: xlb = hb @ Wg (bf16 MFMA, f32 accum) ----------------
__global__ __launch_bounds__(256) void k_gemm_bf16(const u16* __restrict__ hb,
                                                   const u16* __restrict__ WgT,
                                                   u16* __restrict__ xlb) {
    __shared__ u16 As[64 * 32];
    __shared__ u16 Bs[256 * 32];

    const int tid = threadIdx.x;
    const int w = tid >> 6;
    const int l = tid & 63;
    const int m0 = blockIdx.x * 64;

    f32x4 acc[4][4] = {};

    const size_t a_src = (size_t)(m0 + w * 16 + (l >> 2)) * WIDTH + (size_t)((l & 3) * 8);
    u16* const as_dst = As + w * 16 * 32;

    for (int ks = 0; ks < 8; ++ks) {
        const int k0 = ks * 32;
        __builtin_amdgcn_global_load_lds(
            (const __attribute__((address_space(1))) u32*)(hb + a_src + k0),
            (__attribute__((address_space(3))) u32*)as_dst, 16, 0, 0);
#pragma unroll
        for (int j = 0; j < 4; ++j) {
            const u16* bsrc = WgT + (size_t)(w * 64 + j * 16 + (l >> 2)) * WIDTH + k0 + (l & 3) * 8;
            __builtin_amdgcn_global_load_lds(
                (const __attribute__((address_space(1))) u32*)bsrc,
                (__attribute__((address_space(3))) u32*)(Bs + (w * 64 + j * 16) * 32), 16, 0, 0);
        }
        asm volatile("s_waitcnt vmcnt(0)" ::: "memory");
        __syncthreads();

        bf16x8 a[4], b[4];
#pragma unroll
        for (int fr = 0; fr < 4; ++fr)
            a[fr] = *reinterpret_cast<const bf16x8*>(&As[(fr * 16 + (l & 15)) * 32 + (l >> 4) * 8]);
#pragma unroll
        for (int fc = 0; fc < 4; ++fc)
            b[fc] = *reinterpret_cast<const bf16x8*>(&Bs[(w * 64 + fc * 16 + (l & 15)) * 32 + (l >> 4) * 8]);
#pragma unroll
        for (int fr = 0; fr < 4; ++fr)
#pragma unroll
            for (int fc = 0; fc < 4; ++fc)
                acc[fr][fc] = __builtin_amdgcn_mfma_f32_16x16x32_bf16(a[fr], b[fc], acc[fr][fc], 0, 0, 0);
        __syncthreads();
    }

    const int r0 = (l >> 4) * 4;
    const int ci = l & 15;
#pragma unroll
    for (int fr = 0; fr < 4; ++fr)
#pragma unroll
        for (int fc = 0; fc < 4; ++fc) {
            const int col = w * 64 + fc * 16 + ci;
#pragma unroll
            for (int r = 0; r < 4; ++r) {
                const int row = m0 + fr * 16 + r0 + r;
                xlb[(size_t)row * WIDTH + col] = f2b(acc[fr][fc][r]);
            }
        }
}

// ---------------- fused aggregate: one WAVE per node, shuffle-broadcast edges ----------------
// h[i] += bg + dis[i]^2*xl[i] + dis[i]*sum_e dis[s]*xl[s];  hb = bf16(h)
// lane L owns channels 4L..4L+3 (ushort4 = 8B gather per lane per edge)
__global__ __launch_bounds__(256) void k_aggregate(const int* __restrict__ off,
                                                   const int* __restrict__ csr_src,
                                                   const float* __restrict__ dis,
                                                   const u16* __restrict__ xlb,
                                                   const float* __restrict__ bg,
                                                   float* __restrict__ h,
                                                   u16* __restrict__ hb, int N) {
    const int i = (blockIdx.x * 256 + threadIdx.x) >> 6;   // node = global wave id
    if (i >= N) return;
    const int lane = threadIdx.x & 63;
    const int e0 = off[i];
    const int e1 = off[i + 1];
    const float di = dis[i];

    float acc[4] = {0.f, 0.f, 0.f, 0.f};

    for (int base = e0; base < e1; base += 64) {
        const int m = min(64, e1 - base);
        int s = 0;
        float ds = 0.0f;
        if (lane < m) {
            s = csr_src[base + lane];
            ds = dis[s];
        }
        int j = 0;
        for (; j + 4 <= m; j += 4) {
            const int s0 = __shfl(s, j + 0), s1 = __shfl(s, j + 1);
            const int s2 = __shfl(s, j + 2), s3 = __shfl(s, j + 3);
            const float d0 = __shfl(ds, j + 0), d1 = __shfl(ds, j + 1);
            const float d2 = __shfl(ds, j + 2), d3 = __shfl(ds, j + 3);
            const uint2 v0 = *reinterpret_cast<const uint2*>(&xlb[(size_t)s0 * WIDTH + lane * 4]);
            const uint2 v1 = *reinterpret_cast<const uint2*>(&xlb[(size_t)s1 * WIDTH + lane * 4]);
            const uint2 v2 = *reinterpret_cast<const uint2*>(&xlb[(size_t)s2 * WIDTH + lane * 4]);
            const uint2 v3 = *reinterpret_cast<const uint2*>(&xlb[(size_t)s3 * WIDTH + lane * 4]);
            acc[0] = fmaf(d0, b2f_lo(v0.x), acc[0]);
            acc[1] = fmaf(d0, b2f_hi(v0.x), acc[1]);
            acc[2] = fmaf(d0, b2f_lo(v0.y), acc[2]);
            acc[3] = fmaf(d0, b2f_hi(v0.y), acc[3]);
            acc[0] = fmaf(d1, b2f_lo(v1.x), acc[0]);
            acc[1] = fmaf(d1, b2f_hi(v1.x), acc[1]);
            acc[2] = fmaf(d1, b2f_lo(v1.y), acc[2]);
            acc[3] = fmaf(d1, b2f_hi(v1.y), acc[3]);
            acc[0] = fmaf(d2, b2f_lo(v2.x), acc[0]);
            acc[1] = fmaf(d2, b2f_hi(v2.x), acc[1]);
            acc[2] = fmaf(d2, b2f_lo(v2.y), acc[2]);
            acc[3] = fmaf(d2, b2f_hi(v2.y), acc[3]);
            acc[0] = fmaf(d3, b2f_lo(v3.x), acc[0]);
            acc[1] = fmaf(d3, b2f_hi(v3.x), acc[1]);
            acc[2] = fmaf(d3, b2f_lo(v3.y), acc[2]);
            acc[3] = fmaf(d3, b2f_hi(v3.y), acc[3]);
        }
        for (; j < m; ++j) {
            const int sj = __shfl(s, j);
            const float dj = __shfl(ds, j);
            const uint2 v = *reinterpret_cast<const uint2*>(&xlb[(size_t)sj * WIDTH + lane * 4]);
            acc[0] = fmaf(dj, b2f_lo(v.x), acc[0]);
            acc[1] = fmaf(dj, b2f_hi(v.x), acc[1]);
            acc[2] = fmaf(dj, b2f_lo(v.y), acc[2]);
            acc[3] = fmaf(dj, b2f_hi(v.y), acc[3]);
        }
    }

    const size_t p = (size_t)i * WIDTH + lane * 4;
    const float4 hv = *reinterpret_cast<const float4*>(&h[p]);
    const uint2 sv = *reinterpret_cast<const uint2*>(&xlb[p]);
    const float4 bv = *reinterpret_cast<const float4*>(&bg[lane * 4]);
    const float dd = di * di;
    float4 o;
    o.x = hv.x + bv.x + dd * b2f_lo(sv.x) + di * acc[0];
    o.y = hv.y + bv.y + dd * b2f_hi(sv.x) + di * acc[1];
    o.z = hv.z + bv.z + dd * b2f_lo(sv.y) + di * acc[2];
    o.w = hv.w + bv.w + dd * b2f_hi(sv.y) + di * acc[3];
    *reinterpret_cast<float4*>(&h[p]) = o;
    ushort4 ob;
    ob.x = f2b(o.x); ob.y = f2b(o.y); ob.z = f2b(o.z); ob.w = f2b(o.w);
    *reinterpret_cast<ushort4*>(&hb[p]) = ob;
}

// ---------------- head ----------------
__global__ __launch_bounds__(256) void k_head(const float* __restrict__ h,
                                              const int* __restrict__ center,
                                              const int* __restrict__ ptr,
                                              const float* __restrict__ Wh,
                                              const float* __restrict__ bh,
                                              float* __restrict__ out) {
    __shared__ float gs[256];
    const int g = blockIdx.x;
    const int node = center[g] + ptr[g];
    gs[threadIdx.x] = gelu_exact(h[(size_t)node * WIDTH + threadIdx.x]);
    __syncthreads();
    if (threadIdx.x < 7) {
        float acc = bh[threadIdx.x];
        for (int k = 0; k < 256; ++k)
            acc = fmaf(gs[k], Wh[threadIdx.x * 256 + k], acc);
        out[g * 7 + threadIdx.x] = acc;
    }
}

extern "C" void kernel_launch(void* const* d_in, const int* in_sizes, int n_in,
                              void* d_out, int out_size, void* d_ws, size_t ws_size,
                              hipStream_t stream) {
    const float* x      = (const float*)d_in[0];
    const int*   ei     = (const int*)d_in[1];
    const int*   center = (const int*)d_in[2];
    const int*   ptr    = (const int*)d_in[3];
    const float* Wf     = (const float*)d_in[4];
    const float* bf     = (const float*)d_in[5];
    const float* Wg     = (const float*)d_in[6];
    const float* bg     = (const float*)d_in[7];
    const float* Wh     = (const float*)d_in[8];
    const float* bh     = (const float*)d_in[9];

    const int E = in_sizes[1] / 2;       // 799744
    const int N = in_sizes[0] / 64;      // 49984
    const int B = in_sizes[2];           // 32

    char* ws = (char*)d_ws;
    size_t o = 0;
    float* h       = (float*)(ws + o); o += (size_t)N * WIDTH * 4;   // 51.2 MB
    u16*   hb      = (u16*)  (ws + o); o += (size_t)N * WIDTH * 2;   // 25.6 MB
    u16*   xlb     = (u16*)  (ws + o); o += (size_t)N * WIDTH * 2;   // 25.6 MB
    float* dis     = (float*)(ws + o); o += (size_t)N * 4;
    int*   deg     = (int*)  (ws + o); o += (size_t)N * 4;
    int*   off     = (int*)  (ws + o); o += (size_t)(N + 1) * 4;
    int*   cursor  = (int*)  (ws + o); o += (size_t)N * 4;
    int*   part    = (int*)  (ws + o); o += 1024;
    int*   csr_src = (int*)  (ws + o); o += (size_t)E * 4;           // 3.2 MB
    u16*   WgT     = (u16*)  (ws + o); o += (size_t)4 * 65536 * 2;   // 0.5 MB

    const int* rowv = ei;
    const int* colv = ei + E;

    const int nb = (N + 255) / 256;   // 196
    const int eb = (E + 255) / 256;

    k_zero_int<<<nb, 256, 0, stream>>>(deg, N);
    k_hist<<<eb, 256, 0, stream>>>(colv, deg, E);
    k_dis<<<nb, 256, 0, stream>>>(deg, dis, N);
    k_scan1<<<nb, 256, 0, stream>>>(deg, off, part, N);
    k_scan2<<<1, 256, 0, stream>>>(part, nb);
    k_scan3<<<nb, 256, 0, stream>>>(off, part, cursor, N, E);
    k_fill<<<eb, 256, 0, stream>>>(rowv, colv, cursor, csr_src, E);

    k_prep_wgt<<<(4 * 65536 + 255) / 256, 256, 0, stream>>>(Wg, WgT, 4 * 65536);

    dim3 gg(N / 64, 4);
    k_gemm_foot<64><<<gg, 256, 0, stream>>>(x, Wf, bf, h, hb);

    const int agg_blocks = (N + 3) / 4;   // 4 waves (nodes) per block
    for (int l = 0; l < 4; ++l) {
        k_gemm_bf16<<<N / 64, 256, 0, stream>>>(hb, WgT + (size_t)l * 65536, xlb);
        k_aggregate<<<agg_blocks, 256, 0, stream>>>(off, csr_src, dis, xlb, bg + (size_t)l * WIDTH, h, hb, N);
    }

    k_head<<<B, 256, 0, stream>>>(h, center, ptr, Wh, bh, (float*)d_out);
}

// Round 5
// 510.967 us; speedup vs baseline: 21.8466x; 1.0114x over previous
//
#include <hip/hip_runtime.h>
#include <math.h>

#define WIDTH 256
typedef unsigned short u16;
typedef unsigned int u32;
typedef __attribute__((ext_vector_type(4))) float f32x4;
typedef __attribute__((ext_vector_type(8))) short bf16x8;

__device__ __forceinline__ float gelu_exact(float v) {
    return 0.5f * v * (1.0f + erff(v * 0.70710678118654752f));
}
__device__ __forceinline__ u16 f2b(float x) {   // f32 -> bf16 RTNE
    u32 u = __builtin_bit_cast(u32, x);
    return (u16)((u + 0x7fffu + ((u >> 16) & 1u)) >> 16);
}
__device__ __forceinline__ float b2f_lo(u32 v) {   // low u16 -> f32
    return __builtin_bit_cast(float, v << 16);
}
__device__ __forceinline__ float b2f_hi(u32 v) {   // high u16 -> f32
    return __builtin_bit_cast(float, v & 0xffff0000u);
}
__device__ __forceinline__ u32 pack2(float a, float b) {
    return (u32)f2b(a) | ((u32)f2b(b) << 16);
}

// ---------------- CSR build ----------------
__global__ void k_zero_int(int* __restrict__ p, int n) {
    int i = blockIdx.x * blockDim.x + threadIdx.x;
    if (i < n) p[i] = 0;
}

__global__ void k_hist(const int* __restrict__ col, int* __restrict__ deg, int E) {
    int i = blockIdx.x * blockDim.x + threadIdx.x;
    if (i < E) atomicAdd(&deg[col[i]], 1);
}

// per-block scan of deg -> off (block-local), part totals; also dis = rsqrt(1+deg)
__global__ __launch_bounds__(256) void k_scan1(const int* __restrict__ deg, int* __restrict__ off,
                                               int* __restrict__ part, float* __restrict__ dis, int N) {
    __shared__ int buf[256];
    const int t = threadIdx.x;
    const int gid = blockIdx.x * 256 + t;
    const int v = (gid < N) ? deg[gid] : 0;
    if (gid < N) dis[gid] = rsqrtf(1.0f + (float)v);
    buf[t] = v;
    __syncthreads();
#pragma unroll
    for (int d = 1; d < 256; d <<= 1) {
        int add = (t >= d) ? buf[t - d] : 0;
        __syncthreads();
        buf[t] += add;
        __syncthreads();
    }
    if (gid < N) off[gid] = buf[t] - v;
    if (t == 255) part[blockIdx.x] = buf[255];
}

__global__ __launch_bounds__(256) void k_scan2(int* __restrict__ part, int NB) {
    __shared__ int buf[256];
    const int t = threadIdx.x;
    int v = (t < NB) ? part[t] : 0;
    buf[t] = v;
    __syncthreads();
#pragma unroll
    for (int d = 1; d < 256; d <<= 1) {
        int add = (t >= d) ? buf[t - d] : 0;
        __syncthreads();
        buf[t] += add;
        __syncthreads();
    }
    if (t < NB) part[t] = buf[t] - v;
}

__global__ __launch_bounds__(256) void k_scan3(int* __restrict__ off, const int* __restrict__ part,
                                               int* __restrict__ cursor, int N, int E) {
    const int gid = blockIdx.x * 256 + threadIdx.x;
    if (gid < N) {
        int o = off[gid] + part[blockIdx.x];
        off[gid] = o;
        cursor[gid] = o;
    }
    if (gid == 0) off[N] = E;
}

__global__ void k_fill(const int* __restrict__ row, const int* __restrict__ col,
                       int* __restrict__ cursor, int* __restrict__ csr_src, int E) {
    int i = blockIdx.x * blockDim.x + threadIdx.x;
    if (i < E) {
        int pos = atomicAdd(&cursor[col[i]], 1);
        csr_src[pos] = row[i];
    }
}

// ---------------- weight prep: WgT (transpose) + WfT (copy) to bf16 ----------------
__global__ void k_prep_w(const float* __restrict__ Wg, const float* __restrict__ Wf,
                         u16* __restrict__ WgT, u16* __restrict__ WfT) {
    int idx = blockIdx.x * blockDim.x + threadIdx.x;
    if (idx < 4 * 65536) {
        int l = idx >> 16;
        int k = (idx >> 8) & 255;
        int n = idx & 255;
        WgT[(size_t)l * 65536 + (size_t)n * 256 + k] = f2b(Wg[idx]);
    } else {
        int j = idx - 4 * 65536;
        if (j < 256 * 64) WfT[j] = f2b(Wf[j]);   // Wf already [n][k]
    }
}

// ---------------- x f32 -> bf16 (8 elems/thread) ----------------
__global__ __launch_bounds__(256) void k_x2b(const float* __restrict__ x, u16* __restrict__ xb, int total8) {
    int i = blockIdx.x * 256 + threadIdx.x;
    if (i >= total8) return;
    const float4 v0 = *reinterpret_cast<const float4*>(&x[(size_t)i * 8]);
    const float4 v1 = *reinterpret_cast<const float4*>(&x[(size_t)i * 8 + 4]);
    uint4 o;
    o.x = pack2(v0.x, v0.y);
    o.y = pack2(v0.z, v0.w);
    o.z = pack2(v1.x, v1.y);
    o.w = pack2(v1.z, v1.w);
    *reinterpret_cast<uint4*>(&xb[(size_t)i * 8]) = o;
}

// ---------------- MFMA GEMM: C[M,256] = A[M,KDIM](bf16) @ BT[256,KDIM]^T ----------------
// block = 64 rows x 256 cols, 4 waves; wave w owns cols [64w, 64w+64); k-steps of 32.
// FOOT: C = gelu(acc + bias[col]) -> Cf (f32) + Cb (bf16). else: Cb = bf16(acc).
template <int KDIM, bool FOOT>
__global__ __launch_bounds__(256) void k_gemm_mfma(const u16* __restrict__ A,
                                                   const u16* __restrict__ BT,
                                                   const float* __restrict__ bias,
                                                   u16* __restrict__ Cb,
                                                   float* __restrict__ Cf) {
    __shared__ u16 As[64 * 32];    // A[row][k] row-major, row stride 32
    __shared__ u16 Bs[256 * 32];   // B^T[n][k] row-major

    const int tid = threadIdx.x;
    const int w = tid >> 6;
    const int l = tid & 63;
    const int m0 = blockIdx.x * 64;

    f32x4 acc[4][4] = {};

    const size_t a_src = (size_t)(m0 + w * 16 + (l >> 2)) * KDIM + (size_t)((l & 3) * 8);
    u16* const as_dst = As + w * 16 * 32;

#pragma unroll
    for (int ks = 0; ks < KDIM / 32; ++ks) {
        const int k0 = ks * 32;
        __builtin_amdgcn_global_load_lds(
            (const __attribute__((address_space(1))) u32*)(A + a_src + k0),
            (__attribute__((address_space(3))) u32*)as_dst, 16, 0, 0);
#pragma unroll
        for (int j = 0; j < 4; ++j) {
            const u16* bsrc = BT + (size_t)(w * 64 + j * 16 + (l >> 2)) * KDIM + k0 + (l & 3) * 8;
            __builtin_amdgcn_global_load_lds(
                (const __attribute__((address_space(1))) u32*)bsrc,
                (__attribute__((address_space(3))) u32*)(Bs + (w * 64 + j * 16) * 32), 16, 0, 0);
        }
        asm volatile("s_waitcnt vmcnt(0)" ::: "memory");
        __syncthreads();

        bf16x8 a[4], b[4];
#pragma unroll
        for (int fr = 0; fr < 4; ++fr)
            a[fr] = *reinterpret_cast<const bf16x8*>(&As[(fr * 16 + (l & 15)) * 32 + (l >> 4) * 8]);
#pragma unroll
        for (int fc = 0; fc < 4; ++fc)
            b[fc] = *reinterpret_cast<const bf16x8*>(&Bs[(w * 64 + fc * 16 + (l & 15)) * 32 + (l >> 4) * 8]);
#pragma unroll
        for (int fr = 0; fr < 4; ++fr)
#pragma unroll
            for (int fc = 0; fc < 4; ++fc)
                acc[fr][fc] = __builtin_amdgcn_mfma_f32_16x16x32_bf16(a[fr], b[fc], acc[fr][fc], 0, 0, 0);
        __syncthreads();
    }

    const int r0 = (l >> 4) * 4;
    const int ci = l & 15;
#pragma unroll
    for (int fr = 0; fr < 4; ++fr)
#pragma unroll
        for (int fc = 0; fc < 4; ++fc) {
            const int col = w * 64 + fc * 16 + ci;
#pragma unroll
            for (int r = 0; r < 4; ++r) {
                const int row = m0 + fr * 16 + r0 + r;
                if (FOOT) {
                    const float o = gelu_exact(acc[fr][fc][r] + bias[col]);
                    Cf[(size_t)row * WIDTH + col] = o;
                    Cb[(size_t)row * WIDTH + col] = f2b(o);
                } else {
                    Cb[(size_t)row * WIDTH + col] = f2b(acc[fr][fc][r]);
                }
            }
        }
}

// ---------------- fused aggregate: 2 nodes per wave (32 lanes each), 16B gathers ----------------
// h[i] += bg + dis[i]^2*xl[i] + dis[i]*sum_e dis[s]*xl[s];  hb = bf16(h)
// half-lane hl owns channels 8hl..8hl+7 (uint4 = 16B per edge row)
__global__ __launch_bounds__(256) void k_aggregate(const int* __restrict__ off,
                                                   const int* __restrict__ csr_src,
                                                   const float* __restrict__ dis,
                                                   const u16* __restrict__ xlb,
                                                   const float* __restrict__ bg,
                                                   float* __restrict__ h,
                                                   u16* __restrict__ hb, int N) {
    const int node = (blockIdx.x * 256 + threadIdx.x) >> 5;   // 32-lane group = node
    if (node >= N) return;
    const int hl = threadIdx.x & 31;
    const int e0 = off[node];
    const int e1 = off[node + 1];
    const float di = dis[node];

    float acc[8] = {};

#define EDGE_FMA(vv, dd_)                          \
    acc[0] = fmaf(dd_, b2f_lo(vv.x), acc[0]);      \
    acc[1] = fmaf(dd_, b2f_hi(vv.x), acc[1]);      \
    acc[2] = fmaf(dd_, b2f_lo(vv.y), acc[2]);      \
    acc[3] = fmaf(dd_, b2f_hi(vv.y), acc[3]);      \
    acc[4] = fmaf(dd_, b2f_lo(vv.z), acc[4]);      \
    acc[5] = fmaf(dd_, b2f_hi(vv.z), acc[5]);      \
    acc[6] = fmaf(dd_, b2f_lo(vv.w), acc[6]);      \
    acc[7] = fmaf(dd_, b2f_hi(vv.w), acc[7]);

    for (int base = e0; base < e1; base += 32) {
        const int m = min(32, e1 - base);
        int s = 0;
        float ds = 0.0f;
        if (hl < m) {
            s = csr_src[base + hl];
            ds = dis[s];
        }
        int j = 0;
        for (; j + 4 <= m; j += 4) {
            const int s0 = __shfl(s, j + 0, 32), s1 = __shfl(s, j + 1, 32);
            const int s2 = __shfl(s, j + 2, 32), s3 = __shfl(s, j + 3, 32);
            const float d0 = __shfl(ds, j + 0, 32), d1 = __shfl(ds, j + 1, 32);
            const float d2 = __shfl(ds, j + 2, 32), d3 = __shfl(ds, j + 3, 32);
            const uint4 v0 = *reinterpret_cast<const uint4*>(&xlb[(size_t)s0 * WIDTH + hl * 8]);
            const uint4 v1 = *reinterpret_cast<const uint4*>(&xlb[(size_t)s1 * WIDTH + hl * 8]);
            const uint4 v2 = *reinterpret_cast<const uint4*>(&xlb[(size_t)s2 * WIDTH + hl * 8]);
            const uint4 v3 = *reinterpret_cast<const uint4*>(&xlb[(size_t)s3 * WIDTH + hl * 8]);
            EDGE_FMA(v0, d0)
            EDGE_FMA(v1, d1)
            EDGE_FMA(v2, d2)
            EDGE_FMA(v3, d3)
        }
        for (; j < m; ++j) {
            const int sj = __shfl(s, j, 32);
            const float dj = __shfl(ds, j, 32);
            const uint4 v = *reinterpret_cast<const uint4*>(&xlb[(size_t)sj * WIDTH + hl * 8]);
            EDGE_FMA(v, dj)
        }
    }
#undef EDGE_FMA

    const size_t p = (size_t)node * WIDTH + hl * 8;
    const uint4 sv = *reinterpret_cast<const uint4*>(&xlb[p]);
    const float4 h0 = *reinterpret_cast<const float4*>(&h[p]);
    const float4 h1 = *reinterpret_cast<const float4*>(&h[p + 4]);
    const float4 b0 = *reinterpret_cast<const float4*>(&bg[hl * 8]);
    const float4 b1 = *reinterpret_cast<const float4*>(&bg[hl * 8 + 4]);
    const float dd = di * di;
    float o[8];
    o[0] = h0.x + b0.x + dd * b2f_lo(sv.x) + di * acc[0];
    o[1] = h0.y + b0.y + dd * b2f_hi(sv.x) + di * acc[1];
    o[2] = h0.z + b0.z + dd * b2f_lo(sv.y) + di * acc[2];
    o[3] = h0.w + b0.w + dd * b2f_hi(sv.y) + di * acc[3];
    o[4] = h1.x + b1.x + dd * b2f_lo(sv.z) + di * acc[4];
    o[5] = h1.y + b1.y + dd * b2f_hi(sv.z) + di * acc[5];
    o[6] = h1.z + b1.z + dd * b2f_lo(sv.w) + di * acc[6];
    o[7] = h1.w + b1.w + dd * b2f_hi(sv.w) + di * acc[7];
    float4 w0, w1;
    w0.x = o[0]; w0.y = o[1]; w0.z = o[2]; w0.w = o[3];
    w1.x = o[4]; w1.y = o[5]; w1.z = o[6]; w1.w = o[7];
    *reinterpret_cast<float4*>(&h[p]) = w0;
    *reinterpret_cast<float4*>(&h[p + 4]) = w1;
    uint4 ob;
    ob.x = pack2(o[0], o[1]);
    ob.y = pack2(o[2], o[3]);
    ob.z = pack2(o[4], o[5]);
    ob.w = pack2(o[6], o[7]);
    *reinterpret_cast<uint4*>(&hb[p]) = ob;
}

// ---------------- head ----------------
__global__ __launch_bounds__(256) void k_head(const float* __restrict__ h,
                                              const int* __restrict__ center,
                                              const int* __restrict__ ptr,
                                              const float* __restrict__ Wh,
                                              const float* __restrict__ bh,
                                              float* __restrict__ out) {
    __shared__ float gs[256];
    const int g = blockIdx.x;
    const int node = center[g] + ptr[g];
    gs[threadIdx.x] = gelu_exact(h[(size_t)node * WIDTH + threadIdx.x]);
    __syncthreads();
    if (threadIdx.x < 7) {
        float acc = bh[threadIdx.x];
        for (int k = 0; k < 256; ++k)
            acc = fmaf(gs[k], Wh[threadIdx.x * 256 + k], acc);
        out[g * 7 + threadIdx.x] = acc;
    }
}

extern "C" void kernel_launch(void* const* d_in, const int* in_sizes, int n_in,
                              void* d_out, int out_size, void* d_ws, size_t ws_size,
                              hipStream_t stream) {
    const float* x      = (const float*)d_in[0];
    const int*   ei     = (const int*)d_in[1];
    const int*   center = (const int*)d_in[2];
    const int*   ptr    = (const int*)d_in[3];
    const float* Wf     = (const float*)d_in[4];
    const float* bf     = (const float*)d_in[5];
    const float* Wg     = (const float*)d_in[6];
    const float* bg     = (const float*)d_in[7];
    const float* Wh     = (const float*)d_in[8];
    const float* bh     = (const float*)d_in[9];

    const int E = in_sizes[1] / 2;       // 799744
    const int N = in_sizes[0] / 64;      // 49984
    const int B = in_sizes[2];           // 32

    char* ws = (char*)d_ws;
    size_t o = 0;
    float* h       = (float*)(ws + o); o += (size_t)N * WIDTH * 4;   // 51.2 MB
    u16*   hb      = (u16*)  (ws + o); o += (size_t)N * WIDTH * 2;   // 25.6 MB
    u16*   xlb     = (u16*)  (ws + o); o += (size_t)N * WIDTH * 2;   // 25.6 MB
    u16*   xb      = (u16*)  (ws + o); o += (size_t)N * 64 * 2;      // 6.4 MB
    float* dis     = (float*)(ws + o); o += (size_t)N * 4;
    int*   deg     = (int*)  (ws + o); o += (size_t)N * 4;
    int*   off     = (int*)  (ws + o); o += (size_t)(N + 1) * 4;
    int*   cursor  = (int*)  (ws + o); o += (size_t)N * 4;
    int*   part    = (int*)  (ws + o); o += 1024;
    int*   csr_src = (int*)  (ws + o); o += (size_t)E * 4;           // 3.2 MB
    u16*   WgT     = (u16*)  (ws + o); o += (size_t)4 * 65536 * 2;   // 0.5 MB
    u16*   WfT     = (u16*)  (ws + o); o += (size_t)256 * 64 * 2;    // 32 KB

    const int* rowv = ei;
    const int* colv = ei + E;

    const int nb = (N + 255) / 256;   // 196
    const int eb = (E + 255) / 256;

    // CSR by destination + norm
    k_zero_int<<<nb, 256, 0, stream>>>(deg, N);
    k_hist<<<eb, 256, 0, stream>>>(colv, deg, E);
    k_scan1<<<nb, 256, 0, stream>>>(deg, off, part, dis, N);
    k_scan2<<<1, 256, 0, stream>>>(part, nb);
    k_scan3<<<nb, 256, 0, stream>>>(off, part, cursor, N, E);
    k_fill<<<eb, 256, 0, stream>>>(rowv, colv, cursor, csr_src, E);

    // bf16 weight/input prep
    k_prep_w<<<(4 * 65536 + 256 * 64 + 255) / 256, 256, 0, stream>>>(Wg, Wf, WgT, WfT);
    k_x2b<<<(N * 64 / 8 + 255) / 256, 256, 0, stream>>>(x, xb, N * 64 / 8);

    // foot: h = gelu(xb @ WfT^T + bf) via MFMA; writes h f32 + hb bf16
    k_gemm_mfma<64, true><<<N / 64, 256, 0, stream>>>(xb, WfT, bf, hb, h);

    const int agg_blocks = N / 8;   // 8 nodes (32-lane groups) per block
    for (int l = 0; l < 4; ++l) {
        k_gemm_mfma<256, false><<<N / 64, 256, 0, stream>>>(hb, WgT + (size_t)l * 65536, nullptr, xlb, nullptr);
        k_aggregate<<<agg_blocks, 256, 0, stream>>>(off, csr_src, dis, xlb, bg + (size_t)l * WIDTH, h, hb, N);
    }

    k_head<<<B, 256, 0, stream>>>(h, center, ptr, Wh, bh, (float*)d_out);
}

// Round 6
// 494.827 us; speedup vs baseline: 22.5591x; 1.0326x over previous
//
#include <hip/hip_runtime.h>
#include <math.h>

#define WIDTH 256
typedef unsigned short u16;
typedef unsigned int u32;
typedef __attribute__((ext_vector_type(4))) float f32x4;
typedef __attribute__((ext_vector_type(8))) short bf16x8;

__device__ __forceinline__ float gelu_exact(float v) {
    return 0.5f * v * (1.0f + erff(v * 0.70710678118654752f));
}
__device__ __forceinline__ u16 f2b(float x) {   // f32 -> bf16 RTNE
    u32 u = __builtin_bit_cast(u32, x);
    return (u16)((u + 0x7fffu + ((u >> 16) & 1u)) >> 16);
}
__device__ __forceinline__ float b2f_lo(u32 v) {
    return __builtin_bit_cast(float, v << 16);
}
__device__ __forceinline__ float b2f_hi(u32 v) {
    return __builtin_bit_cast(float, v & 0xffff0000u);
}
__device__ __forceinline__ u32 pack2(float a, float b) {
    return (u32)f2b(a) | ((u32)f2b(b) << 16);
}

// ---------------- CSR build ----------------
__global__ void k_hist(const int* __restrict__ col, int* __restrict__ deg, int E) {
    int i = blockIdx.x * blockDim.x + threadIdx.x;
    if (i < E) atomicAdd(&deg[col[i]], 1);
}

__global__ __launch_bounds__(256) void k_scan1(const int* __restrict__ deg, int* __restrict__ off,
                                               int* __restrict__ part, float* __restrict__ dis, int N) {
    __shared__ int buf[256];
    const int t = threadIdx.x;
    const int gid = blockIdx.x * 256 + t;
    const int v = (gid < N) ? deg[gid] : 0;
    if (gid < N) dis[gid] = rsqrtf(1.0f + (float)v);
    buf[t] = v;
    __syncthreads();
#pragma unroll
    for (int d = 1; d < 256; d <<= 1) {
        int add = (t >= d) ? buf[t - d] : 0;
        __syncthreads();
        buf[t] += add;
        __syncthreads();
    }
    if (gid < N) off[gid] = buf[t] - v;
    if (t == 255) part[blockIdx.x] = buf[255];
}

__global__ __launch_bounds__(256) void k_scan2(int* __restrict__ part, int NB) {
    __shared__ int buf[256];
    const int t = threadIdx.x;
    int v = (t < NB) ? part[t] : 0;
    buf[t] = v;
    __syncthreads();
#pragma unroll
    for (int d = 1; d < 256; d <<= 1) {
        int add = (t >= d) ? buf[t - d] : 0;
        __syncthreads();
        buf[t] += add;
        __syncthreads();
    }
    if (t < NB) part[t] = buf[t] - v;
}

__global__ __launch_bounds__(256) void k_scan3(int* __restrict__ off, const int* __restrict__ part,
                                               int* __restrict__ cursor, int N, int E) {
    const int gid = blockIdx.x * 256 + threadIdx.x;
    if (gid < N) {
        int o = off[gid] + part[blockIdx.x];
        off[gid] = o;
        cursor[gid] = o;
    }
    if (gid == 0) off[N] = E;
}

__global__ void k_fill(const int* __restrict__ row, const int* __restrict__ col,
                       int* __restrict__ cursor, int* __restrict__ csr_src, int E) {
    int i = blockIdx.x * blockDim.x + threadIdx.x;
    if (i < E) {
        int pos = atomicAdd(&cursor[col[i]], 1);
        csr_src[pos] = row[i];
    }
}

// ---------------- weight prep: WgT (transpose) + WfT (copy) to bf16 ----------------
__global__ void k_prep_w(const float* __restrict__ Wg, const float* __restrict__ Wf,
                         u16* __restrict__ WgT, u16* __restrict__ WfT) {
    int idx = blockIdx.x * blockDim.x + threadIdx.x;
    if (idx < 4 * 65536) {
        int l = idx >> 16;
        int k = (idx >> 8) & 255;
        int n = idx & 255;
        WgT[(size_t)l * 65536 + (size_t)n * 256 + k] = f2b(Wg[idx]);
    } else {
        int j = idx - 4 * 65536;
        if (j < 256 * 64) WfT[j] = f2b(Wf[j]);   // Wf already [n][k]
    }
}

// ---------------- x f32 -> bf16 ----------------
__global__ __launch_bounds__(256) void k_x2b(const float* __restrict__ x, u16* __restrict__ xb, int total8) {
    int i = blockIdx.x * 256 + threadIdx.x;
    if (i >= total8) return;
    const float4 v0 = *reinterpret_cast<const float4*>(&x[(size_t)i * 8]);
    const float4 v1 = *reinterpret_cast<const float4*>(&x[(size_t)i * 8 + 4]);
    uint4 o;
    o.x = pack2(v0.x, v0.y);
    o.y = pack2(v0.z, v0.w);
    o.z = pack2(v1.x, v1.y);
    o.w = pack2(v1.z, v1.w);
    *reinterpret_cast<uint4*>(&xb[(size_t)i * 8]) = o;
}

// ---------------- MFMA GEMM v2: C[M,256] = A[M,KDIM](bf16) @ BT[256,KDIM]^T ----------------
// block = 64 rows x 256 cols, 4 waves; wave w owns cols [64w,64w+64); BK=64 (2 mfma-K per
// LDS tile). LDS rows are 128B -> XOR swizzle slot^=(row&7) (16B slots); staged via
// pre-swizzled GLOBAL source + linear LDS dest (global_load_lds is linear-only), read with
// the same XOR. Residual aliasing 2-way (free).
template <int KDIM, bool FOOT>
__global__ __launch_bounds__(256) void k_gemm_mfma(const u16* __restrict__ A,
                                                   const u16* __restrict__ BT,
                                                   const float* __restrict__ bias,
                                                   u16* __restrict__ Cb,
                                                   float* __restrict__ Cf) {
    __shared__ u16 As[64 * 64];    // [row][64k], swizzled slots, 8 KB
    __shared__ u16 Bs[256 * 64];   // [n][64k],  swizzled slots, 32 KB

    const int tid = threadIdx.x;
    const int w = tid >> 6;
    const int l = tid & 63;
    const int m0 = blockIdx.x * 64;

    const int lr = l >> 3;                 // row within an 8-row staging group
    const int lc = l & 7;                  // linear LDS slot this lane fills
    const int src_slot = lc ^ lr;          // inverse-swizzled global slot

    f32x4 acc[4][4] = {};

#pragma unroll
    for (int ks = 0; ks < KDIM / 64; ++ks) {
        const int k0 = ks * 64;
        // A: wave w stages rows [16w,16w+16) — 2 instrs
#pragma unroll
        for (int i = 0; i < 2; ++i) {
            const u16* asrc = A + (size_t)(m0 + 16 * w + 8 * i + lr) * KDIM + k0 + src_slot * 8;
            __builtin_amdgcn_global_load_lds(
                (const __attribute__((address_space(1))) u32*)asrc,
                (__attribute__((address_space(3))) u32*)(As + (16 * w + 8 * i) * 64), 16, 0, 0);
        }
        // B: wave w stages n-rows [64w,64w+64) — 8 instrs
#pragma unroll
        for (int j = 0; j < 8; ++j) {
            const u16* bsrc = BT + (size_t)(64 * w + 8 * j + lr) * KDIM + k0 + src_slot * 8;
            __builtin_amdgcn_global_load_lds(
                (const __attribute__((address_space(1))) u32*)bsrc,
                (__attribute__((address_space(3))) u32*)(Bs + (64 * w + 8 * j) * 64), 16, 0, 0);
        }
        asm volatile("s_waitcnt vmcnt(0)" ::: "memory");
        __syncthreads();

        bf16x8 a[4][2], b[4][2];
#pragma unroll
        for (int fr = 0; fr < 4; ++fr) {
            const int row = fr * 16 + (l & 15);
#pragma unroll
            for (int kk = 0; kk < 2; ++kk)
                a[fr][kk] = *reinterpret_cast<const bf16x8*>(
                    &As[row * 64 + ((kk * 4 + (l >> 4)) ^ (row & 7)) * 8]);
        }
#pragma unroll
        for (int fc = 0; fc < 4; ++fc) {
            const int row = 64 * w + fc * 16 + (l & 15);
#pragma unroll
            for (int kk = 0; kk < 2; ++kk)
                b[fc][kk] = *reinterpret_cast<const bf16x8*>(
                    &Bs[row * 64 + ((kk * 4 + (l >> 4)) ^ (row & 7)) * 8]);
        }
#pragma unroll
        for (int fr = 0; fr < 4; ++fr)
#pragma unroll
            for (int fc = 0; fc < 4; ++fc) {
                acc[fr][fc] = __builtin_amdgcn_mfma_f32_16x16x32_bf16(a[fr][0], b[fc][0], acc[fr][fc], 0, 0, 0);
                acc[fr][fc] = __builtin_amdgcn_mfma_f32_16x16x32_bf16(a[fr][1], b[fc][1], acc[fr][fc], 0, 0, 0);
            }
        __syncthreads();
    }

    const int r0 = (l >> 4) * 4;
    const int ci = l & 15;
#pragma unroll
    for (int fr = 0; fr < 4; ++fr)
#pragma unroll
        for (int fc = 0; fc < 4; ++fc) {
            const int col = w * 64 + fc * 16 + ci;
#pragma unroll
            for (int r = 0; r < 4; ++r) {
                const int row = m0 + fr * 16 + r0 + r;
                if (FOOT) {
                    const float o = gelu_exact(acc[fr][fc][r] + bias[col]);
                    Cf[(size_t)row * WIDTH + col] = o;
                    Cb[(size_t)row * WIDTH + col] = f2b(o);
                } else {
                    Cb[(size_t)row * WIDTH + col] = f2b(acc[fr][fc][r]);
                }
            }
        }
}

// ---------------- fused aggregate: 2 nodes per wave (32 lanes each) ----------------
// h[i] += bg + dis[i]*( dis[i]*xl[i] + sum_e dis[s]*xl[s] );  hb = bf16(h)
// self-loop handled as a virtual edge through the same gather path.
__global__ __launch_bounds__(256) void k_aggregate(const int* __restrict__ off,
                                                   const int* __restrict__ csr_src,
                                                   const float* __restrict__ dis,
                                                   const u16* __restrict__ xlb,
                                                   const float* __restrict__ bg,
                                                   float* __restrict__ h,
                                                   u16* __restrict__ hb, int N) {
    const int node = (blockIdx.x * 256 + threadIdx.x) >> 5;
    if (node >= N) return;
    const int hl = threadIdx.x & 31;
    const int e0 = off[node];
    const int e1 = off[node + 1];
    const float di = dis[node];

    float acc[8];

#define EDGE_FMA(vv, dd_)                          \
    acc[0] = fmaf(dd_, b2f_lo(vv.x), acc[0]);      \
    acc[1] = fmaf(dd_, b2f_hi(vv.x), acc[1]);      \
    acc[2] = fmaf(dd_, b2f_lo(vv.y), acc[2]);      \
    acc[3] = fmaf(dd_, b2f_hi(vv.y), acc[3]);      \
    acc[4] = fmaf(dd_, b2f_lo(vv.z), acc[4]);      \
    acc[5] = fmaf(dd_, b2f_hi(vv.z), acc[5]);      \
    acc[6] = fmaf(dd_, b2f_lo(vv.w), acc[6]);      \
    acc[7] = fmaf(dd_, b2f_hi(vv.w), acc[7]);

    // self-loop as first gather (row is L2/L3-hot)
    {
        const uint4 v = *reinterpret_cast<const uint4*>(&xlb[(size_t)node * WIDTH + hl * 8]);
        acc[0] = di * b2f_lo(v.x); acc[1] = di * b2f_hi(v.x);
        acc[2] = di * b2f_lo(v.y); acc[3] = di * b2f_hi(v.y);
        acc[4] = di * b2f_lo(v.z); acc[5] = di * b2f_hi(v.z);
        acc[6] = di * b2f_lo(v.w); acc[7] = di * b2f_hi(v.w);
    }

    for (int base = e0; base < e1; base += 32) {
        const int m = min(32, e1 - base);
        int s = 0;
        float ds = 0.0f;
        if (hl < m) {
            s = csr_src[base + hl];
            ds = dis[s];
        }
        int j = 0;
        for (; j + 8 <= m; j += 8) {
            uint4 vv[8];
            float dd[8];
#pragma unroll
            for (int q = 0; q < 8; ++q) {
                const int sq = __shfl(s, j + q, 32);
                dd[q] = __shfl(ds, j + q, 32);
                vv[q] = *reinterpret_cast<const uint4*>(&xlb[(size_t)sq * WIDTH + hl * 8]);
            }
#pragma unroll
            for (int q = 0; q < 8; ++q) { EDGE_FMA(vv[q], dd[q]) }
        }
        if (j + 4 <= m) {
            uint4 vv[4];
            float dd[4];
#pragma unroll
            for (int q = 0; q < 4; ++q) {
                const int sq = __shfl(s, j + q, 32);
                dd[q] = __shfl(ds, j + q, 32);
                vv[q] = *reinterpret_cast<const uint4*>(&xlb[(size_t)sq * WIDTH + hl * 8]);
            }
#pragma unroll
            for (int q = 0; q < 4; ++q) { EDGE_FMA(vv[q], dd[q]) }
            j += 4;
        }
        for (; j < m; ++j) {
            const int sj = __shfl(s, j, 32);
            const float dj = __shfl(ds, j, 32);
            const uint4 v = *reinterpret_cast<const uint4*>(&xlb[(size_t)sj * WIDTH + hl * 8]);
            EDGE_FMA(v, dj)
        }
    }
#undef EDGE_FMA

    const size_t p = (size_t)node * WIDTH + hl * 8;
    const float4 h0 = *reinterpret_cast<const float4*>(&h[p]);
    const float4 h1 = *reinterpret_cast<const float4*>(&h[p + 4]);
    const float4 b0 = *reinterpret_cast<const float4*>(&bg[hl * 8]);
    const float4 b1 = *reinterpret_cast<const float4*>(&bg[hl * 8 + 4]);
    float o[8];
    o[0] = h0.x + b0.x + di * acc[0];
    o[1] = h0.y + b0.y + di * acc[1];
    o[2] = h0.z + b0.z + di * acc[2];
    o[3] = h0.w + b0.w + di * acc[3];
    o[4] = h1.x + b1.x + di * acc[4];
    o[5] = h1.y + b1.y + di * acc[5];
    o[6] = h1.z + b1.z + di * acc[6];
    o[7] = h1.w + b1.w + di * acc[7];
    float4 w0, w1;
    w0.x = o[0]; w0.y = o[1]; w0.z = o[2]; w0.w = o[3];
    w1.x = o[4]; w1.y = o[5]; w1.z = o[6]; w1.w = o[7];
    *reinterpret_cast<float4*>(&h[p]) = w0;
    *reinterpret_cast<float4*>(&h[p + 4]) = w1;
    uint4 ob;
    ob.x = pack2(o[0], o[1]);
    ob.y = pack2(o[2], o[3]);
    ob.z = pack2(o[4], o[5]);
    ob.w = pack2(o[6], o[7]);
    *reinterpret_cast<uint4*>(&hb[p]) = ob;
}

// ---------------- head ----------------
__global__ __launch_bounds__(256) void k_head(const float* __restrict__ h,
                                              const int* __restrict__ center,
                                              const int* __restrict__ ptr,
                                              const float* __restrict__ Wh,
                                              const float* __restrict__ bh,
                                              float* __restrict__ out) {
    __shared__ float gs[256];
    const int g = blockIdx.x;
    const int node = center[g] + ptr[g];
    gs[threadIdx.x] = gelu_exact(h[(size_t)node * WIDTH + threadIdx.x]);
    __syncthreads();
    if (threadIdx.x < 7) {
        float acc = bh[threadIdx.x];
        for (int k = 0; k < 256; ++k)
            acc = fmaf(gs[k], Wh[threadIdx.x * 256 + k], acc);
        out[g * 7 + threadIdx.x] = acc;
    }
}

extern "C" void kernel_launch(void* const* d_in, const int* in_sizes, int n_in,
                              void* d_out, int out_size, void* d_ws, size_t ws_size,
                              hipStream_t stream) {
    const float* x      = (const float*)d_in[0];
    const int*   ei     = (const int*)d_in[1];
    const int*   center = (const int*)d_in[2];
    const int*   ptr    = (const int*)d_in[3];
    const float* Wf     = (const float*)d_in[4];
    const float* bf     = (const float*)d_in[5];
    const float* Wg     = (const float*)d_in[6];
    const float* bg     = (const float*)d_in[7];
    const float* Wh     = (const float*)d_in[8];
    const float* bh     = (const float*)d_in[9];

    const int E = in_sizes[1] / 2;       // 799744
    const int N = in_sizes[0] / 64;      // 49984
    const int B = in_sizes[2];           // 32

    char* ws = (char*)d_ws;
    size_t o = 0;
    float* h       = (float*)(ws + o); o += (size_t)N * WIDTH * 4;   // 51.2 MB
    u16*   hb      = (u16*)  (ws + o); o += (size_t)N * WIDTH * 2;   // 25.6 MB
    u16*   xlb     = (u16*)  (ws + o); o += (size_t)N * WIDTH * 2;   // 25.6 MB
    u16*   xb      = (u16*)  (ws + o); o += (size_t)N * 64 * 2;      // 6.4 MB
    float* dis     = (float*)(ws + o); o += (size_t)N * 4;
    int*   deg     = (int*)  (ws + o); o += (size_t)N * 4;
    int*   off     = (int*)  (ws + o); o += (size_t)(N + 1) * 4;
    int*   cursor  = (int*)  (ws + o); o += (size_t)N * 4;
    int*   part    = (int*)  (ws + o); o += 1024;
    int*   csr_src = (int*)  (ws + o); o += (size_t)E * 4;           // 3.2 MB
    u16*   WgT     = (u16*)  (ws + o); o += (size_t)4 * 65536 * 2;   // 0.5 MB
    u16*   WfT     = (u16*)  (ws + o); o += (size_t)256 * 64 * 2;    // 32 KB

    const int* rowv = ei;
    const int* colv = ei + E;

    const int nb = (N + 255) / 256;   // 196
    const int eb = (E + 255) / 256;

    // CSR by destination + norm
    hipMemsetAsync(deg, 0, (size_t)N * 4, stream);
    k_hist<<<eb, 256, 0, stream>>>(colv, deg, E);
    k_scan1<<<nb, 256, 0, stream>>>(deg, off, part, dis, N);
    k_scan2<<<1, 256, 0, stream>>>(part, nb);
    k_scan3<<<nb, 256, 0, stream>>>(off, part, cursor, N, E);
    k_fill<<<eb, 256, 0, stream>>>(rowv, colv, cursor, csr_src, E);

    // bf16 weight/input prep
    k_prep_w<<<(4 * 65536 + 256 * 64 + 255) / 256, 256, 0, stream>>>(Wg, Wf, WgT, WfT);
    k_x2b<<<(N * 64 / 8 + 255) / 256, 256, 0, stream>>>(x, xb, N * 64 / 8);

    // foot: h = gelu(xb @ WfT^T + bf) via MFMA; writes h f32 + hb bf16
    k_gemm_mfma<64, true><<<N / 64, 256, 0, stream>>>(xb, WfT, bf, hb, h);

    const int agg_blocks = N / 8;   // 8 nodes (32-lane groups) per block
    for (int l = 0; l < 4; ++l) {
        k_gemm_mfma<256, false><<<N / 64, 256, 0, stream>>>(hb, WgT + (size_t)l * 65536, nullptr, xlb, nullptr);
        k_aggregate<<<agg_blocks, 256, 0, stream>>>(off, csr_src, dis, xlb, bg + (size_t)l * WIDTH, h, hb, N);
    }

    k_head<<<B, 256, 0, stream>>>(h, center, ptr, Wh, bh, (float*)d_out);
}